// Round 8
// baseline (167.192 us; speedup 1.0000x reference)
//
#include <hip/hip_runtime.h>
#include <math.h>

using bf16x8 = __attribute__((ext_vector_type(8))) __bf16;
using f32x4  = __attribute__((ext_vector_type(4))) float;

#if __has_builtin(__builtin_amdgcn_exp2f)
#define EXP2F(x) __builtin_amdgcn_exp2f(x)
#else
#define EXP2F(x) exp2f(x)
#endif

__device__ __forceinline__ unsigned short f2bf(float f) {
  unsigned u = __float_as_uint(f);
  unsigned r = u + 0x7fffu + ((u >> 16) & 1u);
  return (unsigned short)(r >> 16);
}

// HW packed f32->bf16 (RNE, same rounding as f2bf). No builtin on gfx950 -> asm.
__device__ __forceinline__ unsigned cvt_pk_bf16(float a, float b) {
  unsigned r;
  asm("v_cvt_pk_bf16_f32 %0, %1, %2" : "=v"(r) : "v"(a), "v"(b));
  return r;
}
__device__ __forceinline__ uint2 pk4(float a, float b, float c, float d) {
  uint2 r; r.x = cvt_pk_bf16(a, b); r.y = cvt_pk_bf16(c, d); return r;
}

__device__ __forceinline__ f32x4 mfma16(uint4 a, uint4 b, f32x4 c) {
  return __builtin_amdgcn_mfma_f32_16x16x32_bf16(
      __builtin_bit_cast(bf16x8, a), __builtin_bit_cast(bf16x8, b), c, 0, 0, 0);
}
__device__ __forceinline__ float swz_xor16(float v) {
  return __int_as_float(__builtin_amdgcn_ds_swizzle(__float_as_int(v), 0x401F));
}

// B-fragment swizzled layout for mfma_f32_16x16x32_bf16:
// element (k, n) -> chunk index (((n>>4)*2 + (k>>5))*64 + ((k>>3)&3)*16 + (n&15))*8 + (k&7)
#define FRAG_OFF(k, n) (((((n) >> 4) * 2 + ((k) >> 5)) * 64 + (((k) >> 3) & 3) * 16 + ((n) & 15)) * 8 + ((k) & 7))

// attention score prescale: (1/sqrt(8)) * log2(e) folded into AQ/qb2
#define ATT_C 0.51006997f

// ---------------- precompute: bf16 weights + algebraic folds -> d_ws ----------------
// wsb (ushort): W1[3][4096]@0  W2[3][4096]@12288  PM1A@24576  PM2@28672
//               AQ@32768  AK@36864  AV@40960  MO@45056  OUT@49152
// wsf (float):  CpatD[4096]@0 (per-thread D-frag order: [tid][nt*4+r])
//               geoD[4096]@4096 (same order)  qb2@8192 kb2@8256 vb2@8320
__global__ void precompute_kernel(
    const float* __restrict__ conv1_w, const float* __restrict__ conv2_w,
    const float* __restrict__ pm1_w, const float* __restrict__ pm1_b,
    const float* __restrict__ pm2_w,
    const float* __restrict__ q_w, const float* __restrict__ q_b,
    const float* __restrict__ k_w, const float* __restrict__ k_b,
    const float* __restrict__ v_w, const float* __restrict__ v_b,
    const float* __restrict__ in_w, const float* __restrict__ in_b,
    const float* __restrict__ mo_w, const float* __restrict__ out_w,
    const float* __restrict__ pattern, const float* __restrict__ points,
    const int* __restrict__ adjacency,
    unsigned short* __restrict__ wsb, float* __restrict__ wsf) {
  int idx = blockIdx.x * 256 + threadIdx.x;
  if (idx < 12288) {                       // W1_t[oc][c] = conv1_w[oc][c][t]
    int t = idx >> 12, rem = idx & 4095;
    int oc = rem >> 6, c = rem & 63;
    wsb[idx] = f2bf(conv1_w[(oc * 64 + c) * 3 + t]);
  } else if (idx < 24576) {                // W2_t block-diagonal dense
    int i2 = idx - 12288;
    int t = i2 >> 12, rem = i2 & 4095;
    int oc = rem >> 6, ci = rem & 63;
    float v = ((ci >> 4) == (oc >> 4)) ? conv2_w[(oc * 16 + (ci & 15)) * 3 + t] : 0.0f;
    wsb[idx] = f2bf(v);
  } else if (idx < 28672) {                // PM1A = pm1_w[:, :64]
    int rem = idx - 24576;
    wsb[idx] = f2bf(pm1_w[(rem >> 6) * 80 + (rem & 63)]);
  } else if (idx < 32768) {                // PM2
    wsb[idx] = f2bf(pm2_w[idx - 28672]);
  } else if (idx < 36864) {                // AQ = (wq @ q_w) * ATT_C
    int rem = idx - 32768; int c = rem >> 6, k = rem & 63;
    float s = 0.f;
    #pragma unroll 8
    for (int j = 0; j < 64; ++j) s += in_w[c * 64 + j] * q_w[j * 64 + k];
    wsb[idx] = f2bf(s * ATT_C);
  } else if (idx < 40960) {                // AK = wk @ k_w
    int rem = idx - 36864; int c = rem >> 6, k = rem & 63;
    float s = 0.f;
    #pragma unroll 8
    for (int j = 0; j < 64; ++j) s += in_w[(64 + c) * 64 + j] * k_w[j * 64 + k];
    wsb[idx] = f2bf(s);
  } else if (idx < 45056) {                // AV = wv @ v_w
    int rem = idx - 40960; int c = rem >> 6, k = rem & 63;
    float s = 0.f;
    #pragma unroll 8
    for (int j = 0; j < 64; ++j) s += in_w[(128 + c) * 64 + j] * v_w[j * 64 + k];
    wsb[idx] = f2bf(s);
  } else if (idx < 49152) {                // MO
    wsb[idx] = f2bf(mo_w[idx - 45056]);
  } else if (idx < 53248) {                // OUT
    wsb[idx] = f2bf(out_w[idx - 49152]);
  } else if (idx < 57344) {                // CpatD[t][j]: per-thread D-frag order
    int rem = idx - 53248; int t = rem >> 4, j = rem & 15;
    int wq = t >> 6, lq = (t >> 4) & 3, l15 = t & 15;
    int c = wq * 16 + lq * 4 + (j & 3);
    int n = (j >> 2) * 16 + l15;
    float s = pm1_b[c];
    #pragma unroll
    for (int cp = 0; cp < 16; ++cp) s += pm1_w[c * 80 + 64 + cp] * pattern[n * 16 + cp];
    wsf[rem] = s;
  } else if (idx < 61440) {                // geoD[t][j]: geo[n][c] in D-frag order
    int rem = idx - 57344; int t = rem >> 4, j = rem & 15;
    int wq = t >> 6, lq = (t >> 4) & 3, l15 = t & 15;
    int c = wq * 16 + lq * 4 + (j & 3);
    int n = (j >> 2) * 16 + l15;
    float dd = 1e-12f;
    #pragma unroll
    for (int i = 0; i < 3; ++i) { float d = points[n * 3 + i] - points[c * 3 + i]; dd += d * d; }
    float dist = sqrtf(dd);
    wsf[4096 + rem] = (adjacency[n * 64 + c] > 0) ? 0.5f : (-0.1f / (1.0f + dist));
  } else if (idx < 61632) {                // fused qkv biases (q scaled by ATT_C)
    int rem = idx - 61440; int which = rem >> 6, c = rem & 63;
    if (which == 0) {
      float s = in_b[c];
      for (int j = 0; j < 64; ++j) s += in_w[c * 64 + j] * q_b[j];
      wsf[8192 + c] = s * ATT_C;
    } else if (which == 1) {
      float s = in_b[64 + c];
      for (int j = 0; j < 64; ++j) s += in_w[(64 + c) * 64 + j] * k_b[j];
      wsf[8256 + c] = s;
    } else {
      float s = in_b[128 + c];
      for (int j = 0; j < 64; ++j) s += in_w[(128 + c) * 64 + j] * v_b[j];
      wsf[8320 + c] = s;
    }
  }
}

// per-wave 64x64x64 GEMM with PRELOADED A-fragments (weights already in regs)
__device__ __forceinline__ void gemm64r(const bf16x8 a[2], const unsigned short* Bf,
                                        int lane, f32x4 acc[4]) {
  #pragma unroll
  for (int s = 0; s < 2; ++s) {
    #pragma unroll
    for (int nt = 0; nt < 4; ++nt) {
      bf16x8 bb = *reinterpret_cast<const bf16x8*>(Bf + ((nt * 2 + s) * 64 + lane) * 8);
      acc[nt] = __builtin_amdgcn_mfma_f32_16x16x32_bf16(a[s], bb, acc[nt], 0, 0, 0);
    }
  }
}

// LDS pool 35840 B (shorts idx unless noted), phase-overlaid:
//  SLOT_A @0     (8KB):  XF(0-1) PIF(2-3) PFF(4-5) CTXF(6-7) HNF(8-9)
//  SLOT_B @4096  (9216B): Y1F(1-2) T1F(3-4) Q[n][72](5-6)
//  KBASE  @8704  (9216B): K[n][72](5-6a)  P scratch low (6b)
//  VBASE  @13312 (9216B): zero-guard(ph1-2) V[c][72](5-6a) P scratch high (6b)
//  P scratch (6b): 4 waves x 2 buffers x 1152 shorts spanning KBASE..pool end
//  H32 f32 idx 2048, stride 65 (7-8): overlays SLOT_B+KBASE (Q,K dead)
#define SLOT_B 4096
#define KBASE  8704
#define VBASE  13312
#define H32F   2048   /* f32 idx */

__global__ __launch_bounds__(256, 4) void fused_kernel(
    const float* __restrict__ x,
    const unsigned short* __restrict__ wsb, const float* __restrict__ wsf,
    const float* __restrict__ conv1_b, const float* __restrict__ conv2_b,
    const float* __restrict__ pm2_b, const float* __restrict__ mo_b,
    const float* __restrict__ out_b, const float* __restrict__ ln_g,
    const float* __restrict__ ln_beta, float* __restrict__ out) {
  __shared__ __align__(16) unsigned char smem_raw[35840];
  unsigned short* S16 = reinterpret_cast<unsigned short*>(smem_raw);
  float* S32 = reinterpret_cast<float*>(smem_raw);

  const int tid = threadIdx.x;
  const int b = blockIdx.x;
  const int lane = tid & 63;
  const int w = tid >> 6;
  const int l15 = lane & 15;
  const int lq = lane >> 4;
  const int c0 = 16 * w + lq * 4;   // D-frag row base for this lane
  f32x4 pfs[4];                     // pf residual, D-layout, ph4 -> ph7

  // prefetch helpers: weight A-frag for this wave's rows, table offset off
  auto ldw = [&](int off) -> bf16x8 {
    return *reinterpret_cast<const bf16x8*>(wsb + off + (16 * w + l15) * 64 + lq * 8);
  };

  // rotating prefetch registers (assigned before the barrier preceding use)
  bf16x8 a6[3][2];                  // conv weights (W1 then W2)
  bf16x8 pA[2], pB[2];              // generic GEMM A-frag pairs
  f32x4 cp4[4], gd4[4];             // CpatD / geoD addends (per-thread contiguous)
  f32x4 bq4, bk4, mo_b4, ob4;       // prefetched biases
  float bvv[4];                     // V bias per lane channel (ct*16+l15)

  // ---------- Phase 0: zero-guard + stage x -> XF; prefetch conv1 ----------
  if (tid < 8) S16[VBASE + tid] = 0;   // 16B zero chunk for OOB shifted reads
  {
    const float* xb = x + b * 4096 + w * 16 * 64 + lane;
    float v[16];
    #pragma unroll
    for (int j = 0; j < 16; ++j) v[j] = xb[j * 64];
    #pragma unroll
    for (int g = 0; g < 2; ++g) {
      uint4 u;
      u.x = cvt_pk_bf16(v[g * 8 + 0], v[g * 8 + 1]);
      u.y = cvt_pk_bf16(v[g * 8 + 2], v[g * 8 + 3]);
      u.z = cvt_pk_bf16(v[g * 8 + 4], v[g * 8 + 5]);
      u.w = cvt_pk_bf16(v[g * 8 + 6], v[g * 8 + 7]);
      *reinterpret_cast<uint4*>(S16 + FRAG_OFF(w * 16 + g * 8, lane)) = u;
    }
  }
  #pragma unroll
  for (int t = 0; t < 3; ++t) { a6[t][0] = ldw(t * 4096); a6[t][1] = ldw(t * 4096 + 32); }
  f32x4 c1b = *reinterpret_cast<const f32x4*>(conv1_b + c0);
  __syncthreads();

  // ---------- conv helper: sum_t W_t(regs) @ shift(src, t-1), zero-guard ----------
  auto conv_pass = [&](int srcBase, f32x4 acc[4]) {
    #pragma unroll
    for (int nt = 0; nt < 4; ++nt) {
      #pragma unroll
      for (int t = 0; t < 3; ++t) {
        int np = nt * 16 + l15 + (t - 1);
        bool ok = (unsigned)np < 64u;
        int a = srcBase + (((np >> 4) * 2) * 64 + lq * 16 + (np & 15)) * 8;
        int A0 = ok ? a : VBASE;
        int A1 = ok ? (a + 512) : VBASE;
        bf16x8 b0 = *reinterpret_cast<const bf16x8*>(S16 + A0);
        bf16x8 b1 = *reinterpret_cast<const bf16x8*>(S16 + A1);
        acc[nt] = __builtin_amdgcn_mfma_f32_16x16x32_bf16(a6[t][0], b0, acc[nt], 0, 0, 0);
        acc[nt] = __builtin_amdgcn_mfma_f32_16x16x32_bf16(a6[t][1], b1, acc[nt], 0, 0, 0);
      }
    }
  };

  // ---------- Phase 1: conv1 -> Y1F @SLOT_B; prefetch conv2 ----------
  {
    f32x4 acc[4] = {};
    conv_pass(0, acc);
    #pragma unroll
    for (int nt = 0; nt < 4; ++nt) {
      int n = nt * 16 + l15;
      uint2 u = pk4(fmaxf(acc[nt][0] + c1b[0], 0.f), fmaxf(acc[nt][1] + c1b[1], 0.f),
                    fmaxf(acc[nt][2] + c1b[2], 0.f), fmaxf(acc[nt][3] + c1b[3], 0.f));
      *reinterpret_cast<uint2*>(S16 + SLOT_B + FRAG_OFF(c0, n)) = u;
    }
  }
  #pragma unroll
  for (int t = 0; t < 3; ++t) { a6[t][0] = ldw(12288 + t * 4096); a6[t][1] = ldw(12288 + t * 4096 + 32); }
  f32x4 c2b = *reinterpret_cast<const f32x4*>(conv2_b + c0);
  __syncthreads();

  // ---------- Phase 2: conv2 -> PIF @SLOT_A; prefetch PM1A + CpatD ----------
  {
    f32x4 acc[4] = {};
    conv_pass(SLOT_B, acc);
    #pragma unroll
    for (int nt = 0; nt < 4; ++nt) {
      int n = nt * 16 + l15;
      uint2 u = pk4(fmaxf(acc[nt][0] + c2b[0], 0.f), fmaxf(acc[nt][1] + c2b[1], 0.f),
                    fmaxf(acc[nt][2] + c2b[2], 0.f), fmaxf(acc[nt][3] + c2b[3], 0.f));
      *reinterpret_cast<uint2*>(S16 + FRAG_OFF(c0, n)) = u;
    }
  }
  pA[0] = ldw(24576); pA[1] = ldw(24576 + 32);
  #pragma unroll
  for (int k2 = 0; k2 < 4; ++k2)
    cp4[k2] = *reinterpret_cast<const f32x4*>(wsf + tid * 16 + k2 * 4);
  __syncthreads();

  // ---------- Phase 3: pm1: relu(PM1A @ PIF + CpatD) -> T1F @SLOT_B; prefetch PM2 ----------
  {
    f32x4 acc[4] = {};
    gemm64r(pA, S16, lane, acc);
    #pragma unroll
    for (int nt = 0; nt < 4; ++nt) {
      int n = nt * 16 + l15;
      uint2 u = pk4(fmaxf(acc[nt][0] + cp4[nt][0], 0.f),
                    fmaxf(acc[nt][1] + cp4[nt][1], 0.f),
                    fmaxf(acc[nt][2] + cp4[nt][2], 0.f),
                    fmaxf(acc[nt][3] + cp4[nt][3], 0.f));
      *reinterpret_cast<uint2*>(S16 + SLOT_B + FRAG_OFF(c0, n)) = u;
    }
  }
  pA[0] = ldw(28672); pA[1] = ldw(28672 + 32);
  f32x4 p2b = *reinterpret_cast<const f32x4*>(pm2_b + c0);
  __syncthreads();

  // ---------- Phase 4: pm2 -> PFF @SLOT_A + pf regs; prefetch AQ/AK + biases ----------
  {
    f32x4 acc[4] = {};
    gemm64r(pA, S16 + SLOT_B, lane, acc);
    #pragma unroll
    for (int nt = 0; nt < 4; ++nt) {
      int n = nt * 16 + l15;
      f32x4 v;
      #pragma unroll
      for (int r = 0; r < 4; ++r) v[r] = acc[nt][r] + p2b[r];
      pfs[nt] = v;
      *reinterpret_cast<uint2*>(S16 + FRAG_OFF(c0, n)) = pk4(v[0], v[1], v[2], v[3]);
    }
  }
  pA[0] = ldw(32768); pA[1] = ldw(32768 + 32);
  pB[0] = ldw(36864); pB[1] = ldw(36864 + 32);
  bq4 = *reinterpret_cast<const f32x4*>(wsf + 8192 + c0);
  bk4 = *reinterpret_cast<const f32x4*>(wsf + 8256 + c0);
  #pragma unroll
  for (int ct = 0; ct < 4; ++ct) bvv[ct] = wsf[8320 + ct * 16 + l15];
  __syncthreads();

  // ---------- Phase 5: Q@SLOT_B, K@KBASE (bf16 [n][72]); V@VBASE (bf16 [c][72]) ----------
  {
    f32x4 acc[4] = {};
    gemm64r(pA, S16, lane, acc);   // AQ (pre-scaled)
    #pragma unroll
    for (int nt = 0; nt < 4; ++nt) {
      int n = nt * 16 + l15;
      *reinterpret_cast<uint2*>(S16 + SLOT_B + n * 72 + c0) =
          pk4(acc[nt][0] + bq4[0], acc[nt][1] + bq4[1],
              acc[nt][2] + bq4[2], acc[nt][3] + bq4[3]);
    }
  }
  {
    f32x4 acc[4] = {};
    gemm64r(pB, S16, lane, acc);   // AK
    #pragma unroll
    for (int nt = 0; nt < 4; ++nt) {
      int n = nt * 16 + l15;
      *reinterpret_cast<uint2*>(S16 + KBASE + n * 72 + c0) =
          pk4(acc[nt][0] + bk4[0], acc[nt][1] + bk4[1],
              acc[nt][2] + bk4[2], acc[nt][3] + bk4[3]);
    }
  }
  {
    // V computed TRANSPOSED (R6-proven operands): VT[m][c] = sum_j PF[j][m]*AV[c][j]
    //   A-frag = PFF fragment buffer read as B-layout for n-tile w
    //   B-frag = AV rows, loaded PHASE-LOCALLY (L2 latency hides under Q/K GEMMs
    //            above; no cross-barrier live range -> no spill, unlike R6)
    // D-layout: row = token m = 16w+lq*4+r, col = channel c = ct*16+l15
    // -> channel-major V[c][m] store is a vector uint2 write (was 16-way scalar
    //    scatter + 16 f2bf).
    f32x4 acc[4] = {};
    const unsigned short* AV = wsb + 40960;
    #pragma unroll
    for (int s = 0; s < 2; ++s) {
      bf16x8 a = *reinterpret_cast<const bf16x8*>(S16 + ((w * 2 + s) * 64 + lane) * 8);
      #pragma unroll
      for (int ct = 0; ct < 4; ++ct) {
        bf16x8 bb = *reinterpret_cast<const bf16x8*>(
            AV + (ct * 16 + l15) * 64 + s * 32 + lq * 8);
        acc[ct] = __builtin_amdgcn_mfma_f32_16x16x32_bf16(a, bb, acc[ct], 0, 0, 0);
      }
    }
    const int m0 = 16 * w + lq * 4;
    #pragma unroll
    for (int ct = 0; ct < 4; ++ct) {
      int c = ct * 16 + l15;
      float bia = bvv[ct];
      *reinterpret_cast<uint2*>(S16 + VBASE + c * 72 + m0) =
          pk4(acc[ct][0] + bia, acc[ct][1] + bia, acc[ct][2] + bia, acc[ct][3] + bia);
    }
  }
  __syncthreads();

  // ---------- Phase 6: MFMA attention, software-pipelined chains ----------
  {
    const bool lq0 = (lq == 0);
    // 6a: preload V B-frags AND zero-masked K A-frags for BOTH heads.
    uint4 vb[2][2], ka[2][4];
    #pragma unroll
    for (int rr = 0; rr < 2; ++rr) {
      const int h = w + rr * 4;
      #pragma unroll
      for (int ks = 0; ks < 2; ++ks)
        vb[rr][ks] = *reinterpret_cast<const uint4*>(
            S16 + VBASE + (h * 8 + (l15 & 7)) * 72 + ks * 32 + lq * 8);
      #pragma unroll
      for (int mt = 0; mt < 4; ++mt) {
        uint4 t = *reinterpret_cast<const uint4*>(
            S16 + KBASE + (mt * 16 + l15) * 72 + h * 8);
        // zero A-operand rows k>=8 (lanes lq!=0); this alone makes the k>=8
        // products vanish, so the B-side (qb) needs NO masking.
        ka[rr][mt].x = lq0 ? t.x : 0u; ka[rr][mt].y = lq0 ? t.y : 0u;
        ka[rr][mt].z = lq0 ? t.z : 0u; ka[rr][mt].w = lq0 ? t.w : 0u;
      }
    }
    __syncthreads();   // all K/V reads done before P scratch overwrites them

    // 8 chains i = rr*4 + q; double-buffered P scratch; A(i+1) overlaps B(i).
    // P stores UNNORMALIZED e (deferred softmax): ctx scaled by inv in stageB.
    float invb[2];
    auto stageA = [&](int i) {
      const int rr = i >> 2, q = i & 3;
      const int h = w + rr * 4;
      uint4 qb = *reinterpret_cast<const uint4*>(
          S16 + SLOT_B + (q * 16 + l15) * 72 + h * 8);
      f32x4 sc[4];
      #pragma unroll
      for (int mt = 0; mt < 4; ++mt) {
        f32x4 z = {0.f, 0.f, 0.f, 0.f};
        sc[mt] = mfma16(ka[rr][mt], qb, z);   // S[m][n=l15] in exp2 domain
      }
      float sum = 0.f;
      #pragma unroll
      for (int mt = 0; mt < 4; ++mt)
        #pragma unroll
        for (int r = 0; r < 4; ++r) {
          float e = EXP2F(sc[mt][r]);
          sc[mt][r] = e; sum += e;
        }
      const int Pb = KBASE + (w * 2 + (i & 1)) * 1152;
      #pragma unroll
      for (int mt = 0; mt < 4; ++mt) {
        unsigned d0 = __builtin_amdgcn_perm(__float_as_uint(sc[mt][1]),
                                            __float_as_uint(sc[mt][0]), 0x07060302u);
        unsigned d1 = __builtin_amdgcn_perm(__float_as_uint(sc[mt][3]),
                                            __float_as_uint(sc[mt][2]), 0x07060302u);
        *reinterpret_cast<uint2*>(S16 + Pb + l15 * 72 + mt * 16 + lq * 4) =
            make_uint2(d0, d1);
      }
      sum += swz_xor16(sum);
      sum += __shfl_xor(sum, 32);
      invb[i & 1] = __builtin_amdgcn_rcpf(sum);
    };
    auto stageB = [&](int i) {
      const int rr = i >> 2, q = i & 3;
      const int Pb = KBASE + (w * 2 + (i & 1)) * 1152;
      const float inv = invb[i & 1];
      f32x4 ctx = {0.f, 0.f, 0.f, 0.f};
      #pragma unroll
      for (int ks = 0; ks < 2; ++ks) {
        uint4 pa = *reinterpret_cast<const uint4*>(
            S16 + Pb + l15 * 72 + ks * 32 + lq * 8);
        ctx = mfma16(pa, vb[rr][ks], ctx);
      }
      if (l15 < 8) {
        const int kk = (w + rr * 4) * 8 + l15;
        #pragma unroll
        for (int r = 0; r < 4; ++r)
          S16[FRAG_OFF(kk, q * 16 + lq * 4 + r)] = f2bf(ctx[r] * inv);
      }
    };
    stageA(0);
    #pragma unroll
    for (int i = 0; i < 8; ++i) {
      if (i < 7) stageA(i + 1);
      stageB(i);
    }
  }
  // prefetch MO frags + mo_b + geoD (issued before the barrier; used in ph7)
  pA[0] = ldw(45056); pA[1] = ldw(45056 + 32);
  mo_b4 = *reinterpret_cast<const f32x4*>(mo_b + c0);
  #pragma unroll
  for (int k2 = 0; k2 < 4; ++k2)
    gd4[k2] = *reinterpret_cast<const f32x4*>(wsf + 4096 + tid * 16 + k2 * 4);
  __syncthreads();

  // ---------- Phase 7: MO @ CTXF + mo_b + geoD + pf(regs) -> H32 (f32 stride 65) ----------
  {
    f32x4 acc[4] = {};
    gemm64r(pA, S16, lane, acc);
    #pragma unroll
    for (int nt = 0; nt < 4; ++nt) {
      int n = nt * 16 + l15;
      #pragma unroll
      for (int r = 0; r < 4; ++r) {
        int c = c0 + r;
        S32[H32F + c * 65 + n] = acc[nt][r] + mo_b4[r] + gd4[nt][r] + pfs[nt][r];
      }
    }
  }
  __syncthreads();

  // ---------- Phase 8: LayerNorm, WAVE-LOCAL (no internal barriers) ----------
  // Wave w owns columns n in [16w, 16w+16); lane (lq,l15) sums channels
  // [16lq, 16lq+16) of column n = 16w+l15. The 4-way partial reduce is
  // in-register (swz_xor16 + shfl_xor 32) -- replaces 2 barriers + LDS round-trip.
  {
    const int n = 16 * w + l15;
    const int ch0 = lq * 16;
    f32x4 g0 = *reinterpret_cast<const f32x4*>(ln_g + ch0);
    f32x4 g1 = *reinterpret_cast<const f32x4*>(ln_g + ch0 + 4);
    f32x4 g2 = *reinterpret_cast<const f32x4*>(ln_g + ch0 + 8);
    f32x4 g3 = *reinterpret_cast<const f32x4*>(ln_g + ch0 + 12);
    f32x4 e0 = *reinterpret_cast<const f32x4*>(ln_beta + ch0);
    f32x4 e1 = *reinterpret_cast<const f32x4*>(ln_beta + ch0 + 4);
    f32x4 e2 = *reinterpret_cast<const f32x4*>(ln_beta + ch0 + 8);
    f32x4 e3 = *reinterpret_cast<const f32x4*>(ln_beta + ch0 + 12);
    float sum = 0.f, ssq = 0.f;
    float hv[16];
    #pragma unroll
    for (int j = 0; j < 16; ++j) {
      float v = S32[H32F + (ch0 + j) * 65 + n];
      hv[j] = v; sum += v; ssq += v * v;
    }
    // reduce across the 4 lq groups (lanes n, n+16, n+32, n+48)
    sum += swz_xor16(sum);  sum += __shfl_xor(sum, 32);
    ssq += swz_xor16(ssq);  ssq += __shfl_xor(ssq, 32);
    float mu = sum * (1.0f / 64.0f);
    float rs = rsqrtf(ssq * (1.0f / 64.0f) - mu * mu + 1e-5f);
    float gg[16] = {g0[0],g0[1],g0[2],g0[3], g1[0],g1[1],g1[2],g1[3],
                    g2[0],g2[1],g2[2],g2[3], g3[0],g3[1],g3[2],g3[3]};
    float ee[16] = {e0[0],e0[1],e0[2],e0[3], e1[0],e1[1],e1[2],e1[3],
                    e2[0],e2[1],e2[2],e2[3], e3[0],e3[1],e3[2],e3[3]};
    #pragma unroll
    for (int half = 0; half < 2; ++half) {
      float vv[8];
      #pragma unroll
      for (int jj = 0; jj < 8; ++jj) {
        int j = half * 8 + jj;
        vv[jj] = (hv[j] - mu) * rs * gg[j] + ee[j];
      }
      uint4 u;
      u.x = cvt_pk_bf16(vv[0], vv[1]);
      u.y = cvt_pk_bf16(vv[2], vv[3]);
      u.z = cvt_pk_bf16(vv[4], vv[5]);
      u.w = cvt_pk_bf16(vv[6], vv[7]);
      *reinterpret_cast<uint4*>(S16 + FRAG_OFF(ch0 + half * 8, n)) = u;
    }
  }
  // prefetch OUT frags + out_b (used in ph9)
  pA[0] = ldw(49152); pA[1] = ldw(49152 + 32);
  ob4 = *reinterpret_cast<const f32x4*>(out_b + c0);
  __syncthreads();

  // ---------- Phase 9: OUT @ HNF + out_b -> global [b][c][n] ----------
  {
    f32x4 acc[4] = {};
    gemm64r(pA, S16, lane, acc);
    float* ob = out + b * 4096;
    #pragma unroll
    for (int nt = 0; nt < 4; ++nt) {
      int n = nt * 16 + l15;
      #pragma unroll
      for (int r = 0; r < 4; ++r)
        ob[(c0 + r) * 64 + n] = acc[nt][r] + ob4[r];
    }
  }
}

extern "C" void kernel_launch(void* const* d_in, const int* in_sizes, int n_in,
                              void* d_out, int out_size, void* d_ws, size_t ws_size,
                              hipStream_t stream) {
  const float* x        = (const float*)d_in[0];
  const float* points   = (const float*)d_in[1];
  const float* conv1_w  = (const float*)d_in[2];
  const float* conv1_b  = (const float*)d_in[3];
  const float* conv2_w  = (const float*)d_in[4];
  const float* conv2_b  = (const float*)d_in[5];
  const float* pattern  = (const float*)d_in[6];
  const float* pm1_w    = (const float*)d_in[7];
  const float* pm1_b    = (const float*)d_in[8];
  const float* pm2_w    = (const float*)d_in[9];
  const float* pm2_b    = (const float*)d_in[10];
  const float* q_w      = (const float*)d_in[11];
  const float* q_b      = (const float*)d_in[12];
  const float* k_w      = (const float*)d_in[13];
  const float* k_b      = (const float*)d_in[14];
  const float* v_w      = (const float*)d_in[15];
  const float* v_b      = (const float*)d_in[16];
  const float* in_w     = (const float*)d_in[17];
  const float* in_b     = (const float*)d_in[18];
  const float* mo_w     = (const float*)d_in[19];
  const float* mo_b     = (const float*)d_in[20];
  const float* out_w    = (const float*)d_in[21];
  const float* out_b    = (const float*)d_in[22];
  const float* ln_g     = (const float*)d_in[23];
  const float* ln_beta  = (const float*)d_in[24];
  const int*   adjacency= (const int*)d_in[25];

  unsigned short* wsb = (unsigned short*)d_ws;
  float* wsf = (float*)((char*)d_ws + 106496);

  precompute_kernel<<<241, 256, 0, stream>>>(
      conv1_w, conv2_w, pm1_w, pm1_b, pm2_w, q_w, q_b, k_w, k_b, v_w, v_b,
      in_w, in_b, mo_w, out_w, pattern, points, adjacency, wsb, wsf);

  fused_kernel<<<2048, 256, 0, stream>>>(
      x, wsb, wsf, conv1_b, conv2_b, pm2_b, mo_b, out_b, ln_g, ln_beta,
      (float*)d_out);
}

// Round 9
// 165.638 us; speedup vs baseline: 1.0094x; 1.0094x over previous
//
#include <hip/hip_runtime.h>
#include <math.h>

using bf16x8 = __attribute__((ext_vector_type(8))) __bf16;
using f32x4  = __attribute__((ext_vector_type(4))) float;

#if __has_builtin(__builtin_amdgcn_exp2f)
#define EXP2F(x) __builtin_amdgcn_exp2f(x)
#else
#define EXP2F(x) exp2f(x)
#endif

__device__ __forceinline__ unsigned short f2bf(float f) {
  unsigned u = __float_as_uint(f);
  unsigned r = u + 0x7fffu + ((u >> 16) & 1u);
  return (unsigned short)(r >> 16);
}

// HW packed f32->bf16 (RNE, same rounding as f2bf). No builtin on gfx950 -> asm.
__device__ __forceinline__ unsigned cvt_pk_bf16(float a, float b) {
  unsigned r;
  asm("v_cvt_pk_bf16_f32 %0, %1, %2" : "=v"(r) : "v"(a), "v"(b));
  return r;
}
__device__ __forceinline__ uint2 pk4(float a, float b, float c, float d) {
  uint2 r; r.x = cvt_pk_bf16(a, b); r.y = cvt_pk_bf16(c, d); return r;
}

__device__ __forceinline__ f32x4 mfma16(uint4 a, uint4 b, f32x4 c) {
  return __builtin_amdgcn_mfma_f32_16x16x32_bf16(
      __builtin_bit_cast(bf16x8, a), __builtin_bit_cast(bf16x8, b), c, 0, 0, 0);
}
__device__ __forceinline__ float swz_xor16(float v) {
  return __int_as_float(__builtin_amdgcn_ds_swizzle(__float_as_int(v), 0x401F));
}

// B-fragment swizzled layout for mfma_f32_16x16x32_bf16:
// element (k, n) -> chunk index (((n>>4)*2 + (k>>5))*64 + ((k>>3)&3)*16 + (n&15))*8 + (k&7)
#define FRAG_OFF(k, n) (((((n) >> 4) * 2 + ((k) >> 5)) * 64 + (((k) >> 3) & 3) * 16 + ((n) & 15)) * 8 + ((k) & 7))

// attention score prescale: (1/sqrt(8)) * log2(e) folded into AQ/qb2
#define ATT_C 0.51006997f

// ---------------- precompute: bf16 weights + algebraic folds -> d_ws ----------------
// wsb (ushort): W1[3][4096]@0  W2[3][4096]@12288  PM1A@24576  PM2@28672
//               AQ@32768  AK@36864  AV@40960  MO@45056  OUT@49152
// wsf (float):  CpatD[4096]@0 (per-thread D-frag order: [tid][nt*4+r])
//               geoD[4096]@4096 (same order)  qb2@8192 kb2@8256 vb2@8320
__global__ void precompute_kernel(
    const float* __restrict__ conv1_w, const float* __restrict__ conv2_w,
    const float* __restrict__ pm1_w, const float* __restrict__ pm1_b,
    const float* __restrict__ pm2_w,
    const float* __restrict__ q_w, const float* __restrict__ q_b,
    const float* __restrict__ k_w, const float* __restrict__ k_b,
    const float* __restrict__ v_w, const float* __restrict__ v_b,
    const float* __restrict__ in_w, const float* __restrict__ in_b,
    const float* __restrict__ mo_w, const float* __restrict__ out_w,
    const float* __restrict__ pattern, const float* __restrict__ points,
    const int* __restrict__ adjacency,
    unsigned short* __restrict__ wsb, float* __restrict__ wsf) {
  int idx = blockIdx.x * 256 + threadIdx.x;
  if (idx < 12288) {                       // W1_t[oc][c] = conv1_w[oc][c][t]
    int t = idx >> 12, rem = idx & 4095;
    int oc = rem >> 6, c = rem & 63;
    wsb[idx] = f2bf(conv1_w[(oc * 64 + c) * 3 + t]);
  } else if (idx < 24576) {                // W2_t block-diagonal dense
    int i2 = idx - 12288;
    int t = i2 >> 12, rem = i2 & 4095;
    int oc = rem >> 6, ci = rem & 63;
    float v = ((ci >> 4) == (oc >> 4)) ? conv2_w[(oc * 16 + (ci & 15)) * 3 + t] : 0.0f;
    wsb[idx] = f2bf(v);
  } else if (idx < 28672) {                // PM1A = pm1_w[:, :64]
    int rem = idx - 24576;
    wsb[idx] = f2bf(pm1_w[(rem >> 6) * 80 + (rem & 63)]);
  } else if (idx < 32768) {                // PM2
    wsb[idx] = f2bf(pm2_w[idx - 28672]);
  } else if (idx < 36864) {                // AQ = (wq @ q_w) * ATT_C
    int rem = idx - 32768; int c = rem >> 6, k = rem & 63;
    float s = 0.f;
    #pragma unroll 8
    for (int j = 0; j < 64; ++j) s += in_w[c * 64 + j] * q_w[j * 64 + k];
    wsb[idx] = f2bf(s * ATT_C);
  } else if (idx < 40960) {                // AK = wk @ k_w
    int rem = idx - 36864; int c = rem >> 6, k = rem & 63;
    float s = 0.f;
    #pragma unroll 8
    for (int j = 0; j < 64; ++j) s += in_w[(64 + c) * 64 + j] * k_w[j * 64 + k];
    wsb[idx] = f2bf(s);
  } else if (idx < 45056) {                // AV = wv @ v_w
    int rem = idx - 40960; int c = rem >> 6, k = rem & 63;
    float s = 0.f;
    #pragma unroll 8
    for (int j = 0; j < 64; ++j) s += in_w[(128 + c) * 64 + j] * v_w[j * 64 + k];
    wsb[idx] = f2bf(s);
  } else if (idx < 49152) {                // MO
    wsb[idx] = f2bf(mo_w[idx - 45056]);
  } else if (idx < 53248) {                // OUT
    wsb[idx] = f2bf(out_w[idx - 49152]);
  } else if (idx < 57344) {                // CpatD[t][j]: per-thread D-frag order
    int rem = idx - 53248; int t = rem >> 4, j = rem & 15;
    int wq = t >> 6, lq = (t >> 4) & 3, l15 = t & 15;
    int c = wq * 16 + lq * 4 + (j & 3);
    int n = (j >> 2) * 16 + l15;
    float s = pm1_b[c];
    #pragma unroll
    for (int cp = 0; cp < 16; ++cp) s += pm1_w[c * 80 + 64 + cp] * pattern[n * 16 + cp];
    wsf[rem] = s;
  } else if (idx < 61440) {                // geoD[t][j]: geo[n][c] in D-frag order
    int rem = idx - 57344; int t = rem >> 4, j = rem & 15;
    int wq = t >> 6, lq = (t >> 4) & 3, l15 = t & 15;
    int c = wq * 16 + lq * 4 + (j & 3);
    int n = (j >> 2) * 16 + l15;
    float dd = 1e-12f;
    #pragma unroll
    for (int i = 0; i < 3; ++i) { float d = points[n * 3 + i] - points[c * 3 + i]; dd += d * d; }
    float dist = sqrtf(dd);
    wsf[4096 + rem] = (adjacency[n * 64 + c] > 0) ? 0.5f : (-0.1f / (1.0f + dist));
  } else if (idx < 61632) {                // fused qkv biases (q scaled by ATT_C)
    int rem = idx - 61440; int which = rem >> 6, c = rem & 63;
    if (which == 0) {
      float s = in_b[c];
      for (int j = 0; j < 64; ++j) s += in_w[c * 64 + j] * q_b[j];
      wsf[8192 + c] = s * ATT_C;
    } else if (which == 1) {
      float s = in_b[64 + c];
      for (int j = 0; j < 64; ++j) s += in_w[(64 + c) * 64 + j] * k_b[j];
      wsf[8256 + c] = s;
    } else {
      float s = in_b[128 + c];
      for (int j = 0; j < 64; ++j) s += in_w[(128 + c) * 64 + j] * v_b[j];
      wsf[8320 + c] = s;
    }
  }
}

// per-wave 64x64x64 GEMM with PRELOADED A-fragments (weights already in regs)
__device__ __forceinline__ void gemm64r(const bf16x8 a[2], const unsigned short* Bf,
                                        int lane, f32x4 acc[4]) {
  #pragma unroll
  for (int s = 0; s < 2; ++s) {
    #pragma unroll
    for (int nt = 0; nt < 4; ++nt) {
      bf16x8 bb = *reinterpret_cast<const bf16x8*>(Bf + ((nt * 2 + s) * 64 + lane) * 8);
      acc[nt] = __builtin_amdgcn_mfma_f32_16x16x32_bf16(a[s], bb, acc[nt], 0, 0, 0);
    }
  }
}

// DUAL-BATCH block: two 35840-B pools (POOL shorts apart), same internal layout:
//  SLOT_A @0     (8KB):  XF(0-1) PIF(2-3) PFF(4-5) CTXF(6-7) HNF(8-9)
//  SLOT_B @4096  (9216B): Y1F(1-2) T1F(3-4) Q[n][72](5-6)
//  KBASE  @8704  (9216B): K[n][72](5-6a)  P scratch low (6b)
//  VBASE  @13312 (9216B): zero-guard(ph1-2) V[c][72](5-6a) P scratch high (6b)
//  P scratch (6b): 4 waves x 2 buffers x 1152 shorts spanning KBASE..pool end
//  H32 f32 idx 2048, stride 65 (7-8): overlays SLOT_B+KBASE (Q,K dead)
// 2 blocks/CU (143,360 B of 160 KiB LDS); launch_bounds(256,2) -> 256-VGPR budget.
#define POOL   17920  /* shorts per pool (35840 B) */
#define POOLF  8960   /* floats per pool */
#define SLOT_B 4096
#define KBASE  8704
#define VBASE  13312
#define H32F   2048   /* f32 idx */

__global__ __launch_bounds__(256, 2) void fused_kernel(
    const float* __restrict__ x,
    const unsigned short* __restrict__ wsb, const float* __restrict__ wsf,
    const float* __restrict__ conv1_b, const float* __restrict__ conv2_b,
    const float* __restrict__ pm2_b, const float* __restrict__ mo_b,
    const float* __restrict__ out_b, const float* __restrict__ ln_g,
    const float* __restrict__ ln_beta, float* __restrict__ out) {
  __shared__ __align__(16) unsigned char smem_raw[71680];
  unsigned short* S16 = reinterpret_cast<unsigned short*>(smem_raw);
  float* S32 = reinterpret_cast<float*>(smem_raw);

  const int tid = threadIdx.x;
  const int b = blockIdx.x;          // batches 2b and 2b+1
  const int lane = tid & 63;
  const int w = tid >> 6;
  const int l15 = lane & 15;
  const int lq = lane >> 4;
  const int c0 = 16 * w + lq * 4;    // D-frag row base for this lane
  f32x4 pfs[2][4];                   // pf residual per batch, ph4 -> ph7

  auto ldw = [&](int off) -> bf16x8 {
    return *reinterpret_cast<const bf16x8*>(wsb + off + (16 * w + l15) * 64 + lq * 8);
  };

  bf16x8 a6[3][2];                   // conv weights (shared across batches)
  bf16x8 pA[2], pB[2];               // GEMM A-frag pairs (shared)
  f32x4 cp4[4], gd4[4];              // CpatD / geoD addends (batch-independent)
  f32x4 bq4, bk4, mo_b4, ob4;        // biases (shared)
  float bvv[4];                      // V bias per lane channel

  // ---------- Phase 0: zero-guards + stage x (both batches); prefetch conv1 ----------
  if (tid < 8) { S16[VBASE + tid] = 0; S16[POOL + VBASE + tid] = 0; }
  #pragma unroll
  for (int bb = 0; bb < 2; ++bb) {
    const float* xb = x + (2 * b + bb) * 4096 + w * 16 * 64 + lane;
    float v[16];
    #pragma unroll
    for (int j = 0; j < 16; ++j) v[j] = xb[j * 64];
    #pragma unroll
    for (int g = 0; g < 2; ++g) {
      uint4 u;
      u.x = cvt_pk_bf16(v[g * 8 + 0], v[g * 8 + 1]);
      u.y = cvt_pk_bf16(v[g * 8 + 2], v[g * 8 + 3]);
      u.z = cvt_pk_bf16(v[g * 8 + 4], v[g * 8 + 5]);
      u.w = cvt_pk_bf16(v[g * 8 + 6], v[g * 8 + 7]);
      *reinterpret_cast<uint4*>(S16 + bb * POOL + FRAG_OFF(w * 16 + g * 8, lane)) = u;
    }
  }
  #pragma unroll
  for (int t = 0; t < 3; ++t) { a6[t][0] = ldw(t * 4096); a6[t][1] = ldw(t * 4096 + 32); }
  f32x4 c1b = *reinterpret_cast<const f32x4*>(conv1_b + c0);
  __syncthreads();

  // conv: sum_t W_t(regs) @ shift(src, t-1), zero-guard; Sb = pool base
  auto conv_pass = [&](const unsigned short* Sb, int srcBase, f32x4 acc[4]) {
    #pragma unroll
    for (int nt = 0; nt < 4; ++nt) {
      #pragma unroll
      for (int t = 0; t < 3; ++t) {
        int np = nt * 16 + l15 + (t - 1);
        bool ok = (unsigned)np < 64u;
        int a = srcBase + (((np >> 4) * 2) * 64 + lq * 16 + (np & 15)) * 8;
        int A0 = ok ? a : VBASE;
        int A1 = ok ? (a + 512) : VBASE;
        bf16x8 b0 = *reinterpret_cast<const bf16x8*>(Sb + A0);
        bf16x8 b1 = *reinterpret_cast<const bf16x8*>(Sb + A1);
        acc[nt] = __builtin_amdgcn_mfma_f32_16x16x32_bf16(a6[t][0], b0, acc[nt], 0, 0, 0);
        acc[nt] = __builtin_amdgcn_mfma_f32_16x16x32_bf16(a6[t][1], b1, acc[nt], 0, 0, 0);
      }
    }
  };

  // ---------- Phase 1: conv1 (both) -> Y1F @SLOT_B; prefetch conv2 ----------
  {
    f32x4 a0[4] = {}, a1[4] = {};
    conv_pass(S16, 0, a0);
    conv_pass(S16 + POOL, 0, a1);
    #pragma unroll
    for (int nt = 0; nt < 4; ++nt) {
      int n = nt * 16 + l15;
      *reinterpret_cast<uint2*>(S16 + SLOT_B + FRAG_OFF(c0, n)) =
          pk4(fmaxf(a0[nt][0] + c1b[0], 0.f), fmaxf(a0[nt][1] + c1b[1], 0.f),
              fmaxf(a0[nt][2] + c1b[2], 0.f), fmaxf(a0[nt][3] + c1b[3], 0.f));
      *reinterpret_cast<uint2*>(S16 + POOL + SLOT_B + FRAG_OFF(c0, n)) =
          pk4(fmaxf(a1[nt][0] + c1b[0], 0.f), fmaxf(a1[nt][1] + c1b[1], 0.f),
              fmaxf(a1[nt][2] + c1b[2], 0.f), fmaxf(a1[nt][3] + c1b[3], 0.f));
    }
  }
  #pragma unroll
  for (int t = 0; t < 3; ++t) { a6[t][0] = ldw(12288 + t * 4096); a6[t][1] = ldw(12288 + t * 4096 + 32); }
  f32x4 c2b = *reinterpret_cast<const f32x4*>(conv2_b + c0);
  __syncthreads();

  // ---------- Phase 2: conv2 (both) -> PIF @SLOT_A; prefetch PM1A + CpatD ----------
  {
    f32x4 a0[4] = {}, a1[4] = {};
    conv_pass(S16, SLOT_B, a0);
    conv_pass(S16 + POOL, SLOT_B, a1);
    #pragma unroll
    for (int nt = 0; nt < 4; ++nt) {
      int n = nt * 16 + l15;
      *reinterpret_cast<uint2*>(S16 + FRAG_OFF(c0, n)) =
          pk4(fmaxf(a0[nt][0] + c2b[0], 0.f), fmaxf(a0[nt][1] + c2b[1], 0.f),
              fmaxf(a0[nt][2] + c2b[2], 0.f), fmaxf(a0[nt][3] + c2b[3], 0.f));
      *reinterpret_cast<uint2*>(S16 + POOL + FRAG_OFF(c0, n)) =
          pk4(fmaxf(a1[nt][0] + c2b[0], 0.f), fmaxf(a1[nt][1] + c2b[1], 0.f),
              fmaxf(a1[nt][2] + c2b[2], 0.f), fmaxf(a1[nt][3] + c2b[3], 0.f));
    }
  }
  pA[0] = ldw(24576); pA[1] = ldw(24576 + 32);
  #pragma unroll
  for (int k2 = 0; k2 < 4; ++k2)
    cp4[k2] = *reinterpret_cast<const f32x4*>(wsf + tid * 16 + k2 * 4);
  __syncthreads();

  // ---------- Phase 3: pm1 (both) -> T1F @SLOT_B; prefetch PM2 ----------
  {
    f32x4 a0[4] = {}, a1[4] = {};
    gemm64r(pA, S16, lane, a0);
    gemm64r(pA, S16 + POOL, lane, a1);
    #pragma unroll
    for (int nt = 0; nt < 4; ++nt) {
      int n = nt * 16 + l15;
      *reinterpret_cast<uint2*>(S16 + SLOT_B + FRAG_OFF(c0, n)) =
          pk4(fmaxf(a0[nt][0] + cp4[nt][0], 0.f), fmaxf(a0[nt][1] + cp4[nt][1], 0.f),
              fmaxf(a0[nt][2] + cp4[nt][2], 0.f), fmaxf(a0[nt][3] + cp4[nt][3], 0.f));
      *reinterpret_cast<uint2*>(S16 + POOL + SLOT_B + FRAG_OFF(c0, n)) =
          pk4(fmaxf(a1[nt][0] + cp4[nt][0], 0.f), fmaxf(a1[nt][1] + cp4[nt][1], 0.f),
              fmaxf(a1[nt][2] + cp4[nt][2], 0.f), fmaxf(a1[nt][3] + cp4[nt][3], 0.f));
    }
  }
  pA[0] = ldw(28672); pA[1] = ldw(28672 + 32);
  f32x4 p2b = *reinterpret_cast<const f32x4*>(pm2_b + c0);
  __syncthreads();

  // ---------- Phase 4: pm2 (both) -> PFF @SLOT_A + pfs regs; prefetch AQ/AK + biases ----------
  {
    f32x4 a0[4] = {}, a1[4] = {};
    gemm64r(pA, S16 + SLOT_B, lane, a0);
    gemm64r(pA, S16 + POOL + SLOT_B, lane, a1);
    #pragma unroll
    for (int nt = 0; nt < 4; ++nt) {
      int n = nt * 16 + l15;
      f32x4 v0, v1;
      #pragma unroll
      for (int r = 0; r < 4; ++r) { v0[r] = a0[nt][r] + p2b[r]; v1[r] = a1[nt][r] + p2b[r]; }
      pfs[0][nt] = v0; pfs[1][nt] = v1;
      *reinterpret_cast<uint2*>(S16 + FRAG_OFF(c0, n)) = pk4(v0[0], v0[1], v0[2], v0[3]);
      *reinterpret_cast<uint2*>(S16 + POOL + FRAG_OFF(c0, n)) = pk4(v1[0], v1[1], v1[2], v1[3]);
    }
  }
  pA[0] = ldw(32768); pA[1] = ldw(32768 + 32);
  pB[0] = ldw(36864); pB[1] = ldw(36864 + 32);
  bq4 = *reinterpret_cast<const f32x4*>(wsf + 8192 + c0);
  bk4 = *reinterpret_cast<const f32x4*>(wsf + 8256 + c0);
  #pragma unroll
  for (int ct = 0; ct < 4; ++ct) bvv[ct] = wsf[8320 + ct * 16 + l15];
  __syncthreads();

  // ---------- Phase 5: Q/K/V for both batches ----------
  {
    f32x4 a0[4] = {}, a1[4] = {};
    gemm64r(pA, S16, lane, a0);          // AQ batch0
    gemm64r(pA, S16 + POOL, lane, a1);   // AQ batch1
    #pragma unroll
    for (int nt = 0; nt < 4; ++nt) {
      int n = nt * 16 + l15;
      *reinterpret_cast<uint2*>(S16 + SLOT_B + n * 72 + c0) =
          pk4(a0[nt][0] + bq4[0], a0[nt][1] + bq4[1], a0[nt][2] + bq4[2], a0[nt][3] + bq4[3]);
      *reinterpret_cast<uint2*>(S16 + POOL + SLOT_B + n * 72 + c0) =
          pk4(a1[nt][0] + bq4[0], a1[nt][1] + bq4[1], a1[nt][2] + bq4[2], a1[nt][3] + bq4[3]);
    }
  }
  {
    f32x4 a0[4] = {}, a1[4] = {};
    gemm64r(pB, S16, lane, a0);          // AK batch0
    gemm64r(pB, S16 + POOL, lane, a1);   // AK batch1
    #pragma unroll
    for (int nt = 0; nt < 4; ++nt) {
      int n = nt * 16 + l15;
      *reinterpret_cast<uint2*>(S16 + KBASE + n * 72 + c0) =
          pk4(a0[nt][0] + bk4[0], a0[nt][1] + bk4[1], a0[nt][2] + bk4[2], a0[nt][3] + bk4[3]);
      *reinterpret_cast<uint2*>(S16 + POOL + KBASE + n * 72 + c0) =
          pk4(a1[nt][0] + bk4[0], a1[nt][1] + bk4[1], a1[nt][2] + bk4[2], a1[nt][3] + bk4[3]);
    }
  }
  {
    // V TRANSPOSED: VT[m][c] = sum_j PF[j][m]*AV[c][j]; AV frags loaded ONCE,
    // shared by both batches (phase-local -> no cross-barrier pressure).
    bf16x8 av[2][4];
    const unsigned short* AV = wsb + 40960;
    #pragma unroll
    for (int s = 0; s < 2; ++s)
      #pragma unroll
      for (int ct = 0; ct < 4; ++ct)
        av[s][ct] = *reinterpret_cast<const bf16x8*>(AV + (ct * 16 + l15) * 64 + s * 32 + lq * 8);
    const int m0 = 16 * w + lq * 4;
    #pragma unroll
    for (int bb = 0; bb < 2; ++bb) {
      f32x4 acc[4] = {};
      #pragma unroll
      for (int s = 0; s < 2; ++s) {
        bf16x8 a = *reinterpret_cast<const bf16x8*>(S16 + bb * POOL + ((w * 2 + s) * 64 + lane) * 8);
        #pragma unroll
        for (int ct = 0; ct < 4; ++ct)
          acc[ct] = __builtin_amdgcn_mfma_f32_16x16x32_bf16(a, av[s][ct], acc[ct], 0, 0, 0);
      }
      #pragma unroll
      for (int ct = 0; ct < 4; ++ct) {
        int c = ct * 16 + l15;
        float bia = bvv[ct];
        *reinterpret_cast<uint2*>(S16 + bb * POOL + VBASE + c * 72 + m0) =
            pk4(acc[ct][0] + bia, acc[ct][1] + bia, acc[ct][2] + bia, acc[ct][3] + bia);
      }
    }
  }
  __syncthreads();

  // ---------- Phase 6: attention, 16 pipelined chains (2 batches x 2 heads x 4 quarters) ----------
  {
    const bool lq0 = (lq == 0);
    uint4 vb[2][2][2], ka[2][2][4];   // [batch][rr][...]
    #pragma unroll
    for (int bb = 0; bb < 2; ++bb)
      #pragma unroll
      for (int rr = 0; rr < 2; ++rr) {
        const int h = w + rr * 4;
        #pragma unroll
        for (int ks = 0; ks < 2; ++ks)
          vb[bb][rr][ks] = *reinterpret_cast<const uint4*>(
              S16 + bb * POOL + VBASE + (h * 8 + (l15 & 7)) * 72 + ks * 32 + lq * 8);
        #pragma unroll
        for (int mt = 0; mt < 4; ++mt) {
          uint4 t = *reinterpret_cast<const uint4*>(
              S16 + bb * POOL + KBASE + (mt * 16 + l15) * 72 + h * 8);
          ka[bb][rr][mt].x = lq0 ? t.x : 0u; ka[bb][rr][mt].y = lq0 ? t.y : 0u;
          ka[bb][rr][mt].z = lq0 ? t.z : 0u; ka[bb][rr][mt].w = lq0 ? t.w : 0u;
        }
      }
    __syncthreads();   // all K/V reads done before P scratch overwrites them

    // chain i: bb = i&1, j = i>>1, rr = j>>2, q = j&3.
    // P buffer: pool(bb), parity (i>>1)&1 -> same-pool chains alternate buffers.
    // invb[i&1]: consumed by B(i) before A(i+2) overwrites.
    float invb[2];
    auto stageA = [&](int i) {
      const int bb = i & 1, j = i >> 1, rr = j >> 2, q = j & 3;
      const int h = w + rr * 4;
      uint4 qb = *reinterpret_cast<const uint4*>(
          S16 + bb * POOL + SLOT_B + (q * 16 + l15) * 72 + h * 8);
      f32x4 sc[4];
      #pragma unroll
      for (int mt = 0; mt < 4; ++mt) {
        f32x4 z = {0.f, 0.f, 0.f, 0.f};
        sc[mt] = mfma16(ka[bb][rr][mt], qb, z);   // S[m][n=l15] in exp2 domain
      }
      float sum = 0.f;
      #pragma unroll
      for (int mt = 0; mt < 4; ++mt)
        #pragma unroll
        for (int r = 0; r < 4; ++r) {
          float e = EXP2F(sc[mt][r]);
          sc[mt][r] = e; sum += e;
        }
      const int Pb = bb * POOL + KBASE + (w * 2 + ((i >> 1) & 1)) * 1152;
      #pragma unroll
      for (int mt = 0; mt < 4; ++mt) {
        unsigned d0 = __builtin_amdgcn_perm(__float_as_uint(sc[mt][1]),
                                            __float_as_uint(sc[mt][0]), 0x07060302u);
        unsigned d1 = __builtin_amdgcn_perm(__float_as_uint(sc[mt][3]),
                                            __float_as_uint(sc[mt][2]), 0x07060302u);
        *reinterpret_cast<uint2*>(S16 + Pb + l15 * 72 + mt * 16 + lq * 4) =
            make_uint2(d0, d1);
      }
      sum += swz_xor16(sum);
      sum += __shfl_xor(sum, 32);
      invb[i & 1] = __builtin_amdgcn_rcpf(sum);
    };
    auto stageB = [&](int i) {
      const int bb = i & 1, j = i >> 1, rr = j >> 2, q = j & 3;
      const int Pb = bb * POOL + KBASE + (w * 2 + ((i >> 1) & 1)) * 1152;
      const float inv = invb[i & 1];
      f32x4 ctx = {0.f, 0.f, 0.f, 0.f};
      #pragma unroll
      for (int ks = 0; ks < 2; ++ks) {
        uint4 pa = *reinterpret_cast<const uint4*>(
            S16 + Pb + l15 * 72 + ks * 32 + lq * 8);
        ctx = mfma16(pa, vb[bb][rr][ks], ctx);
      }
      if (l15 < 8) {
        const int kk = (w + rr * 4) * 8 + l15;
        #pragma unroll
        for (int r = 0; r < 4; ++r)
          S16[bb * POOL + FRAG_OFF(kk, q * 16 + lq * 4 + r)] = f2bf(ctx[r] * inv);
      }
    };
    stageA(0);
    #pragma unroll
    for (int i = 0; i < 16; ++i) {
      if (i < 15) stageA(i + 1);
      stageB(i);
    }
  }
  pA[0] = ldw(45056); pA[1] = ldw(45056 + 32);
  mo_b4 = *reinterpret_cast<const f32x4*>(mo_b + c0);
  #pragma unroll
  for (int k2 = 0; k2 < 4; ++k2)
    gd4[k2] = *reinterpret_cast<const f32x4*>(wsf + 4096 + tid * 16 + k2 * 4);
  __syncthreads();

  // ---------- Phase 7: MO (both) + mo_b + geoD + pfs -> H32 (f32 stride 65) ----------
  {
    f32x4 a0[4] = {}, a1[4] = {};
    gemm64r(pA, S16, lane, a0);
    gemm64r(pA, S16 + POOL, lane, a1);
    #pragma unroll
    for (int nt = 0; nt < 4; ++nt) {
      int n = nt * 16 + l15;
      #pragma unroll
      for (int r = 0; r < 4; ++r) {
        int c = c0 + r;
        S32[H32F + c * 65 + n] = a0[nt][r] + mo_b4[r] + gd4[nt][r] + pfs[0][nt][r];
        S32[POOLF + H32F + c * 65 + n] = a1[nt][r] + mo_b4[r] + gd4[nt][r] + pfs[1][nt][r];
      }
    }
  }
  __syncthreads();

  // ---------- Phase 8: LayerNorm, WAVE-LOCAL, both batches ----------
  {
    const int n = 16 * w + l15;
    const int ch0 = lq * 16;
    f32x4 g0 = *reinterpret_cast<const f32x4*>(ln_g + ch0);
    f32x4 g1 = *reinterpret_cast<const f32x4*>(ln_g + ch0 + 4);
    f32x4 g2 = *reinterpret_cast<const f32x4*>(ln_g + ch0 + 8);
    f32x4 g3 = *reinterpret_cast<const f32x4*>(ln_g + ch0 + 12);
    f32x4 e0 = *reinterpret_cast<const f32x4*>(ln_beta + ch0);
    f32x4 e1 = *reinterpret_cast<const f32x4*>(ln_beta + ch0 + 4);
    f32x4 e2 = *reinterpret_cast<const f32x4*>(ln_beta + ch0 + 8);
    f32x4 e3 = *reinterpret_cast<const f32x4*>(ln_beta + ch0 + 12);
    float gg[16] = {g0[0],g0[1],g0[2],g0[3], g1[0],g1[1],g1[2],g1[3],
                    g2[0],g2[1],g2[2],g2[3], g3[0],g3[1],g3[2],g3[3]};
    float ee[16] = {e0[0],e0[1],e0[2],e0[3], e1[0],e1[1],e1[2],e1[3],
                    e2[0],e2[1],e2[2],e2[3], e3[0],e3[1],e3[2],e3[3]};
    #pragma unroll
    for (int bb = 0; bb < 2; ++bb) {
      float sum = 0.f, ssq = 0.f;
      float hv[16];
      #pragma unroll
      for (int j = 0; j < 16; ++j) {
        float v = S32[bb * POOLF + H32F + (ch0 + j) * 65 + n];
        hv[j] = v; sum += v; ssq += v * v;
      }
      sum += swz_xor16(sum);  sum += __shfl_xor(sum, 32);
      ssq += swz_xor16(ssq);  ssq += __shfl_xor(ssq, 32);
      float mu = sum * (1.0f / 64.0f);
      float rs = rsqrtf(ssq * (1.0f / 64.0f) - mu * mu + 1e-5f);
      #pragma unroll
      for (int half = 0; half < 2; ++half) {
        float vv[8];
        #pragma unroll
        for (int jj = 0; jj < 8; ++jj) {
          int j = half * 8 + jj;
          vv[jj] = (hv[j] - mu) * rs * gg[j] + ee[j];
        }
        uint4 u;
        u.x = cvt_pk_bf16(vv[0], vv[1]);
        u.y = cvt_pk_bf16(vv[2], vv[3]);
        u.z = cvt_pk_bf16(vv[4], vv[5]);
        u.w = cvt_pk_bf16(vv[6], vv[7]);
        *reinterpret_cast<uint4*>(S16 + bb * POOL + FRAG_OFF(ch0 + half * 8, n)) = u;
      }
    }
  }
  pA[0] = ldw(49152); pA[1] = ldw(49152 + 32);
  ob4 = *reinterpret_cast<const f32x4*>(out_b + c0);
  __syncthreads();

  // ---------- Phase 9: OUT (both) -> global [batch][c][n] ----------
  {
    f32x4 a0[4] = {}, a1[4] = {};
    gemm64r(pA, S16, lane, a0);
    gemm64r(pA, S16 + POOL, lane, a1);
    float* ob0 = out + (2 * b) * 4096;
    float* ob1 = out + (2 * b + 1) * 4096;
    #pragma unroll
    for (int nt = 0; nt < 4; ++nt) {
      int n = nt * 16 + l15;
      #pragma unroll
      for (int r = 0; r < 4; ++r) {
        ob0[(c0 + r) * 64 + n] = a0[nt][r] + ob4[r];
        ob1[(c0 + r) * 64 + n] = a1[nt][r] + ob4[r];
      }
    }
  }
}

extern "C" void kernel_launch(void* const* d_in, const int* in_sizes, int n_in,
                              void* d_out, int out_size, void* d_ws, size_t ws_size,
                              hipStream_t stream) {
  const float* x        = (const float*)d_in[0];
  const float* points   = (const float*)d_in[1];
  const float* conv1_w  = (const float*)d_in[2];
  const float* conv1_b  = (const float*)d_in[3];
  const float* conv2_w  = (const float*)d_in[4];
  const float* conv2_b  = (const float*)d_in[5];
  const float* pattern  = (const float*)d_in[6];
  const float* pm1_w    = (const float*)d_in[7];
  const float* pm1_b    = (const float*)d_in[8];
  const float* pm2_w    = (const float*)d_in[9];
  const float* pm2_b    = (const float*)d_in[10];
  const float* q_w      = (const float*)d_in[11];
  const float* q_b      = (const float*)d_in[12];
  const float* k_w      = (const float*)d_in[13];
  const float* k_b      = (const float*)d_in[14];
  const float* v_w      = (const float*)d_in[15];
  const float* v_b      = (const float*)d_in[16];
  const float* in_w     = (const float*)d_in[17];
  const float* in_b     = (const float*)d_in[18];
  const float* mo_w     = (const float*)d_in[19];
  const float* mo_b     = (const float*)d_in[20];
  const float* out_w    = (const float*)d_in[21];
  const float* out_b    = (const float*)d_in[22];
  const float* ln_g     = (const float*)d_in[23];
  const float* ln_beta  = (const float*)d_in[24];
  const int*   adjacency= (const int*)d_in[25];

  unsigned short* wsb = (unsigned short*)d_ws;
  float* wsf = (float*)((char*)d_ws + 106496);

  precompute_kernel<<<241, 256, 0, stream>>>(
      conv1_w, conv2_w, pm1_w, pm1_b, pm2_w, q_w, q_b, k_w, k_b, v_w, v_b,
      in_w, in_b, mo_w, out_w, pattern, points, adjacency, wsb, wsf);

  fused_kernel<<<1024, 256, 0, stream>>>(
      x, wsb, wsf, conv1_b, conv2_b, pm2_b, mo_b, out_b, ln_g, ln_beta,
      (float*)d_out);
}